// Round 20
// baseline (235.469 us; speedup 1.0000x reference)
//
#include <hip/hip_runtime.h>
#include <hip/hip_bf16.h>
#include <math.h>

typedef unsigned short u16;
typedef unsigned int u32;
typedef __attribute__((ext_vector_type(8))) short bf16x8;
typedef __attribute__((ext_vector_type(4))) float f32x4;

// float -> bf16 (RNE) via HIP native conversion (lowers to v_cvt_pk_bf16_f32)
__device__ __forceinline__ u16 f2b(float f){
  __hip_bfloat16 h = __float2bfloat16(f);
  u16 r;
  __builtin_memcpy(&r, &h, 2);
  return r;
}
__device__ __forceinline__ float b2f(u16 h){ return __uint_as_float(((u32)h) << 16); }

__device__ __forceinline__ void gll16(const void* g, void* l){
  __builtin_amdgcn_global_load_lds((const __attribute__((address_space(1))) void*)g,
                                   (__attribute__((address_space(3))) void*)l, 16, 0, 0);
}

// Fragment-linear layouts (bh = b*16+h), each 131072 u16 per bh:
//  Qf/Kf: idx = bh*131072 + (seq>>4)*1024 + (d>>3)*128 + (seq&15)*8 + (d&7)
//  Vf   : idx = bh*131072 + (k>>5)*2048 + (d>>4)*512 + ((k>>3)&3)*128 + (d&15)*8 + (k&7)
// Q is stored PRE-SCALED by 0.125 (exact power-of-2; commutes with bf16 rounding,
// f32 MFMA accumulation and exp -> bit-identical results, saves a v_mul per exp).

// ---------------- pack kernels ----------------
__global__ __launch_bounds__(256) void pack_x(const float* __restrict__ in, u16* __restrict__ out){
  const int i = blockIdx.x * 256 + threadIdx.x;   // 4096*256 = 1,048,576 float4s exactly
  const float4 v = ((const float4*)in)[i];
  ushort4 o; o.x = f2b(v.x); o.y = f2b(v.y); o.z = f2b(v.z); o.w = f2b(v.w);
  ((ushort4*)out)[i] = o;
}

// batched coalesced transpose: 5 weights in one launch. blockIdx.y selects the matrix.
__global__ __launch_bounds__(256) void pack_wT5(
    const float* __restrict__ w0, const float* __restrict__ w1, const float* __restrict__ w2,
    const float* __restrict__ w3, const float* __restrict__ w4,
    u16* __restrict__ oqkv, u16* __restrict__ o12)
{
  __shared__ u16 t[64][68];
  const int sel = blockIdx.y;
  const float* in = (sel == 0) ? w0 : (sel == 1) ? w1 : (sel == 2) ? w2 : (sel == 3) ? w3 : w4;
  u16* out = (sel < 3) ? (oqkv + (size_t)sel * 1024 * 1024) : (o12 + (size_t)(sel - 3) * 1024 * 1024);
  const int k0 = (blockIdx.x & 15) * 64, n0 = (blockIdx.x >> 4) * 64;
  const int tx = threadIdx.x & 15, ty = threadIdx.x >> 4;
  #pragma unroll
  for (int j = 0; j < 4; ++j){
    const int r = ty + j * 16;
    const float4 v = *(const float4*)&in[(size_t)(k0 + r) * 1024 + n0 + tx * 4];
    t[tx*4+0][r] = f2b(v.x); t[tx*4+1][r] = f2b(v.y);
    t[tx*4+2][r] = f2b(v.z); t[tx*4+3][r] = f2b(v.w);
  }
  __syncthreads();
  #pragma unroll
  for (int j = 0; j < 4; ++j){
    const int c = ty + j * 16;
    *(ushort4*)&out[(size_t)(n0 + c) * 1024 + k0 + tx * 4] = *(const ushort4*)&t[c][tx * 4];
  }
}

// ---------------- 128x128 bf16 GEMM (m97 structure) -- QKV projection, fragment-linear epilogue ----------------
__global__ __launch_bounds__(256) void gemm_qkv(
    const u16* __restrict__ A, const u16* __restrict__ Bt,
    const float* __restrict__ bias0, const float* __restrict__ bias1, const float* __restrict__ bias2,
    u16* __restrict__ o0, u16* __restrict__ o1, u16* __restrict__ o2)
{
  __shared__ __align__(16) u16 As[128 * 32];
  __shared__ __align__(16) u16 Bs[128 * 32];
  const int bm = blockIdx.x, bn = blockIdx.y;
  const int tid = threadIdx.x, w = tid >> 6, l = tid & 63;
  const int wm = (w >> 1) * 64, wn = (w & 1) * 64;
  const u16* Ab = A + (size_t)bm * 128 * 1024;
  const u16* Bb = Bt + (size_t)bn * 128 * 1024;
  const int srow = w * 16 + (l >> 2);
  const int scol = (l & 3) * 8;
  f32x4 acc[4][4];
  #pragma unroll
  for (int m = 0; m < 4; ++m)
    #pragma unroll
    for (int n = 0; n < 4; ++n) acc[m][n] = (f32x4){0.f, 0.f, 0.f, 0.f};
  for (int kt = 0; kt < 32; ++kt){
    const int k0 = kt << 5;
    #pragma unroll
    for (int j = 0; j < 2; ++j){
      gll16(Ab + (size_t)(j * 64 + srow) * 1024 + (k0 + scol), (char*)As + j * 4096 + w * 1024);
      gll16(Bb + (size_t)(j * 64 + srow) * 1024 + (k0 + scol), (char*)Bs + j * 4096 + w * 1024);
    }
    __syncthreads();
    bf16x8 af[4], bfr[4];
    #pragma unroll
    for (int m = 0; m < 4; ++m) af[m]  = *(const bf16x8*)&As[(wm + m * 16 + (l & 15)) * 32 + (l >> 4) * 8];
    #pragma unroll
    for (int n = 0; n < 4; ++n) bfr[n] = *(const bf16x8*)&Bs[(wn + n * 16 + (l & 15)) * 32 + (l >> 4) * 8];
    #pragma unroll
    for (int m = 0; m < 4; ++m)
      #pragma unroll
      for (int n = 0; n < 4; ++n)
        acc[m][n] = __builtin_amdgcn_mfma_f32_16x16x32_bf16(af[m], bfr[n], acc[m][n], 0, 0, 0);
    __syncthreads();
  }
  #pragma unroll
  for (int m = 0; m < 4; ++m){
    #pragma unroll
    for (int n = 0; n < 4; ++n){
      const int row0 = bm * 128 + wm + m * 16 + ((l >> 4) << 2);
      const int col  = bn * 128 + wn + n * 16 + (l & 15);
      const int sec = col >> 10, cw = col & 1023, hh = cw >> 6, d = cw & 63;
      const float bias = (sec == 0 ? bias0 : (sec == 1 ? bias1 : bias2))[cw];
      #pragma unroll
      for (int r = 0; r < 4; ++r){
        const int rr = row0 + r, bi = rr >> 11, seq = rr & 2047;
        const float v = acc[m][n][r] + bias;
        const size_t bhB = (size_t)(bi * 16 + hh) * 131072;
        if (sec < 2){
          const size_t idx = bhB + (size_t)(seq >> 4) * 1024 + (d >> 3) * 128 + (seq & 15) * 8 + (d & 7);
          // Q (sec==0) stored pre-scaled by 1/8 (exact)
          (sec == 0 ? o0 : o1)[idx] = f2b(sec == 0 ? v * 0.125f : v);
        } else {
          const size_t idx = bhB + (size_t)(seq >> 5) * 2048 + (d >> 4) * 512 + ((seq >> 3) & 3) * 128 + (d & 15) * 8 + (seq & 7);
          o2[idx] = f2b(v);
        }
      }
    }
  }
}

// ---------------- 64x128 bf16 GEMM (K=1024), 2 blocks/CU for FFN ----------------
template<int EPI>
__global__ __launch_bounds__(256) void gemm_bt64(
    const u16* __restrict__ A, const u16* __restrict__ Bt,
    const float* __restrict__ bias0,
    u16* __restrict__ o0, const u16* __restrict__ res, float* __restrict__ fo)
{
  __shared__ __align__(16) u16 As[64 * 32];
  __shared__ __align__(16) u16 Bs[128 * 32];
  const int bm = blockIdx.x, bn = blockIdx.y;
  const int tid = threadIdx.x, w = tid >> 6, l = tid & 63;
  const int lo = l & 15, hi = l >> 4;
  const int wm = (w >> 1) * 32, wn = (w & 1) * 64;
  const u16* Ab = A + (size_t)bm * 64 * 1024;
  const u16* Bb = Bt + (size_t)bn * 128 * 1024;
  const int srow = w * 16 + (l >> 2);
  const int scol = (l & 3) * 8;
  f32x4 acc[2][4];
  #pragma unroll
  for (int m = 0; m < 2; ++m)
    #pragma unroll
    for (int n = 0; n < 4; ++n) acc[m][n] = (f32x4){0.f, 0.f, 0.f, 0.f};
  for (int kt = 0; kt < 32; ++kt){
    const int k0 = kt << 5;
    gll16(Ab + (size_t)srow * 1024 + (k0 + scol), (char*)As + w * 1024);
    #pragma unroll
    for (int j = 0; j < 2; ++j)
      gll16(Bb + (size_t)(j * 64 + srow) * 1024 + (k0 + scol), (char*)Bs + j * 4096 + w * 1024);
    __syncthreads();
    bf16x8 af[2], bfr[4];
    #pragma unroll
    for (int m = 0; m < 2; ++m) af[m]  = *(const bf16x8*)&As[(wm + m * 16 + lo) * 32 + hi * 8];
    #pragma unroll
    for (int n = 0; n < 4; ++n) bfr[n] = *(const bf16x8*)&Bs[(wn + n * 16 + lo) * 32 + hi * 8];
    #pragma unroll
    for (int m = 0; m < 2; ++m)
      #pragma unroll
      for (int n = 0; n < 4; ++n)
        acc[m][n] = __builtin_amdgcn_mfma_f32_16x16x32_bf16(af[m], bfr[n], acc[m][n], 0, 0, 0);
    __syncthreads();
  }
  #pragma unroll
  for (int m = 0; m < 2; ++m){
    #pragma unroll
    for (int n = 0; n < 4; ++n){
      const int row0 = bm * 64 + wm + m * 16 + hi * 4;
      const int col  = bn * 128 + wn + n * 16 + lo;
      const float bias = bias0[col];
      if (EPI == 1){
        #pragma unroll
        for (int r = 0; r < 4; ++r){
          const float v = acc[m][n][r] + bias;
          const float gv = 0.5f * v * (1.0f + erff(v * 0.70710678118654752f));
          o0[(size_t)(row0 + r) * 1024 + col] = f2b(gv);
        }
      } else {
        #pragma unroll
        for (int r = 0; r < 4; ++r){
          const float v = acc[m][n][r] + bias + b2f(res[(size_t)(row0 + r) * 1024 + col]);
          fo[(size_t)(row0 + r) * 1024 + col] = v;
        }
      }
    }
  }
}

// ---------------- attention pass 1: denom l only (no max; Q pre-scaled) ----------------
__global__ __launch_bounds__(256) void attn_ml(const u16* __restrict__ Qb, const u16* __restrict__ Kb,
                                               float* __restrict__ ml){
  const int qt = blockIdx.x & 31, bh = blockIdx.x >> 5;
  const int tid = threadIdx.x, w = tid >> 6, l = tid & 63;
  const int lo = l & 15, hi = l >> 4;
  const u16* Qh = Qb + (size_t)bh * 131072;
  const u16* Kh = Kb + (size_t)bh * 131072;
  const int q0 = qt * 64 + w * 16;
  const int s16q = q0 >> 4;
  const bf16x8 qb0 = *(const bf16x8*)&Qh[(size_t)s16q * 1024 + hi * 128 + lo * 8];
  const bf16x8 qb1 = *(const bf16x8*)&Qh[(size_t)s16q * 1024 + (hi + 4) * 128 + lo * 8];
  float l0 = 0.f, l1 = 0.f;
  for (int kt = 0; kt < 128; kt += 2){
    const bf16x8 ka0 = *(const bf16x8*)&Kh[(size_t)kt * 1024 + hi * 128 + lo * 8];
    const bf16x8 ka1 = *(const bf16x8*)&Kh[(size_t)kt * 1024 + (hi + 4) * 128 + lo * 8];
    const bf16x8 kb0 = *(const bf16x8*)&Kh[(size_t)(kt + 1) * 1024 + hi * 128 + lo * 8];
    const bf16x8 kb1 = *(const bf16x8*)&Kh[(size_t)(kt + 1) * 1024 + (hi + 4) * 128 + lo * 8];
    f32x4 s0 = (f32x4){0.f, 0.f, 0.f, 0.f}, s1 = (f32x4){0.f, 0.f, 0.f, 0.f};
    s0 = __builtin_amdgcn_mfma_f32_16x16x32_bf16(ka0, qb0, s0, 0, 0, 0);
    s0 = __builtin_amdgcn_mfma_f32_16x16x32_bf16(ka1, qb1, s0, 0, 0, 0);
    s1 = __builtin_amdgcn_mfma_f32_16x16x32_bf16(kb0, qb0, s1, 0, 0, 0);
    s1 = __builtin_amdgcn_mfma_f32_16x16x32_bf16(kb1, qb1, s1, 0, 0, 0);
    l0 += __expf(s0[0]) + __expf(s0[1]) + __expf(s0[2]) + __expf(s0[3]);
    l1 += __expf(s1[0]) + __expf(s1[1]) + __expf(s1[2]) + __expf(s1[3]);
  }
  float ls = l0 + l1;
  ls += __shfl_xor(ls, 16);
  ls += __shfl_xor(ls, 32);
  if (l < 16) ml[(size_t)bh * 2048 + q0 + l] = ls;
}

// ---------------- fused pass 2 v14: QBLK=32, KS=4, fragment-linear, Q pre-scaled ----------------
// grid = dim3(8, 64): bx = grp = ks*2+b (one XCD per grp), by = qt (32 q rows).
__global__ __launch_bounds__(512) void attn_fused(
    const u16* __restrict__ Qb, const u16* __restrict__ Kb, const u16* __restrict__ Vt,
    const float* __restrict__ ml, const float* __restrict__ Wm, u16* __restrict__ AOp)
{
  __shared__ __align__(16) u16 P2[32 * 32 * 20 + 32];  // [q:32][k:32][h pad20] + guard
  __shared__ __align__(16) u16 A2[32 * 16 * 32];       // byte = q*1024+g*64+2k ^ ((g^q)&7)<<4
  const int grp = blockIdx.x, qt = blockIdx.y;
  const int b = grp & 1, ks = grp >> 1;
  const int tid = threadIdx.x, w = tid >> 6, l = tid & 63;
  const int lo = l & 15, hi = l >> 4;
  const int q0 = qt * 32;

  // zero P2 (pad/guard finite-zero)
  for (int i = tid; i < (32 * 32 * 20 + 32) / 8; i += 512)
    ((uint4*)P2)[i] = (uint4){0u, 0u, 0u, 0u};

  const int h0 = w * 2;
  const u16* Qh0 = Qb + (size_t)(b * 16 + h0) * 131072;
  const u16* Qh1 = Qh0 + 131072;
  const u16* Kh0 = Kb + (size_t)(b * 16 + h0) * 131072;
  const u16* Kh1 = Kh0 + 131072;
  const u16* V0 = Vt + (size_t)(b * 16 + w) * 131072;
  const u16* V1 = Vt + (size_t)(b * 16 + w + 8) * 131072;

  // Q fragments: [qt2][hh][half], rows q = q0 + qt2*16 + lo
  bf16x8 qa[2][2][2];
  #pragma unroll
  for (int qt2 = 0; qt2 < 2; ++qt2){
    const size_t s16 = (size_t)(qt * 2 + qt2) * 1024;
    qa[qt2][0][0] = *(const bf16x8*)&Qh0[s16 + hi * 128 + lo * 8];
    qa[qt2][0][1] = *(const bf16x8*)&Qh0[s16 + (hi + 4) * 128 + lo * 8];
    qa[qt2][1][0] = *(const bf16x8*)&Qh1[s16 + hi * 128 + lo * 8];
    qa[qt2][1][1] = *(const bf16x8*)&Qh1[s16 + (hi + 4) * 128 + lo * 8];
  }

  // softmax inverse denominators: [hh][qt2][r] for rows q = q0 + qt2*16 + hi*4 + r
  float il_[2][2][4];
  #pragma unroll
  for (int hh = 0; hh < 2; ++hh)
    #pragma unroll
    for (int qt2 = 0; qt2 < 2; ++qt2)
      #pragma unroll
      for (int r = 0; r < 4; ++r)
        il_[hh][qt2][r] = 1.0f / ml[(size_t)(b * 16 + h0 + hh) * 2048 + q0 + qt2 * 16 + hi * 4 + r];

  // Wm fragment: B-operand cols g = lo, contraction h = hi*8+i (zero for h>=16)
  bf16x8 wmf;
  #pragma unroll
  for (int i = 0; i < 8; ++i){
    const int hh = hi * 8 + i;
    wmf[i] = (hh < 16) ? (short)f2b(Wm[lo * 16 + hh]) : (short)0;
  }

  f32x4 opv[2][2][4];   // [g2][qt2][nd]
  #pragma unroll
  for (int g2 = 0; g2 < 2; ++g2)
    #pragma unroll
    for (int qt2 = 0; qt2 < 2; ++qt2)
      #pragma unroll
      for (int nd = 0; nd < 4; ++nd) opv[g2][qt2][nd] = (f32x4){0.f, 0.f, 0.f, 0.f};

  __syncthreads();   // P2 zeroing done

  for (int kt = 0; kt < 16; ++kt){
    // ---- issue V loads early: Vf idx = k5*2048 + nd*512 + hi*128 + lo*8, k5 = ks*16+kt ----
    const size_t k5B = (size_t)(ks * 16 + kt) * 2048;
    bf16x8 vb[2][4];
    #pragma unroll
    for (int nd = 0; nd < 4; ++nd){
      vb[0][nd] = *(const bf16x8*)&V0[k5B + nd * 512 + hi * 128 + lo * 8];
      vb[1][nd] = *(const bf16x8*)&V1[k5B + nd * 512 + hi * 128 + lo * 8];
    }
    // ---- phase A: QK^T + softmax for heads h0,h0+1, 32 q rows, 32 k ----
    #pragma unroll
    for (int m = 0; m < 2; ++m){
      const size_t s16k = (size_t)(ks * 32 + kt * 2 + m) * 1024;
      bf16x8 kb[2][2];
      kb[0][0] = *(const bf16x8*)&Kh0[s16k + hi * 128 + lo * 8];
      kb[0][1] = *(const bf16x8*)&Kh0[s16k + (hi + 4) * 128 + lo * 8];
      kb[1][0] = *(const bf16x8*)&Kh1[s16k + hi * 128 + lo * 8];
      kb[1][1] = *(const bf16x8*)&Kh1[s16k + (hi + 4) * 128 + lo * 8];
      #pragma unroll
      for (int qt2 = 0; qt2 < 2; ++qt2){
        f32x4 s0 = (f32x4){0.f, 0.f, 0.f, 0.f}, s1 = (f32x4){0.f, 0.f, 0.f, 0.f};
        s0 = __builtin_amdgcn_mfma_f32_16x16x32_bf16(qa[qt2][0][0], kb[0][0], s0, 0, 0, 0);
        s0 = __builtin_amdgcn_mfma_f32_16x16x32_bf16(qa[qt2][0][1], kb[0][1], s0, 0, 0, 0);
        s1 = __builtin_amdgcn_mfma_f32_16x16x32_bf16(qa[qt2][1][0], kb[1][0], s1, 0, 0, 0);
        s1 = __builtin_amdgcn_mfma_f32_16x16x32_bf16(qa[qt2][1][1], kb[1][1], s1, 0, 0, 0);
        const int k_loc = m * 16 + lo;
        #pragma unroll
        for (int r = 0; r < 4; ++r){
          const float p0 = __expf(s0[r]) * il_[0][qt2][r];
          const float p1 = __expf(s1[r]) * il_[1][qt2][r];
          const u32 pk = (u32)f2b(p0) | ((u32)f2b(p1) << 16);
          const int q_loc = qt2 * 16 + hi * 4 + r;
          *(u32*)((char*)P2 + q_loc * 1280 + k_loc * 40 + w * 4) = pk;
        }
      }
    }
    __syncthreads();   // P2 ready; previous-iter A2 reads complete
    // ---- phase B: talking-heads mix for q-rows w*4..w*4+3 ----
    #pragma unroll
    for (int qq = 0; qq < 4; ++qq){
      const int qr = w * 4 + qq;
      #pragma unroll
      for (int m = 0; m < 2; ++m){
        const bf16x8 pf = *(const bf16x8*)((const char*)P2 + qr * 1280 + (m * 16 + lo) * 40 + hi * 16);
        f32x4 a2 = (f32x4){0.f, 0.f, 0.f, 0.f};
        a2 = __builtin_amdgcn_mfma_f32_16x16x32_bf16(pf, wmf, a2, 0, 0, 0);
        ushort4 o4;
        o4.x = f2b(a2[0]); o4.y = f2b(a2[1]); o4.z = f2b(a2[2]); o4.w = f2b(a2[3]);
        u32 byte = (u32)(qr * 1024 + lo * 64 + m * 32 + hi * 8);
        byte ^= (u32)(((lo ^ qr) & 7) << 4);
        *(ushort4*)((char*)A2 + byte) = o4;
      }
    }
    __syncthreads();   // A2 ready
    // ---- phase C: PV for g = w, w+8 ----
    #pragma unroll
    for (int g2 = 0; g2 < 2; ++g2){
      const int g = w + g2 * 8;
      #pragma unroll
      for (int qt2 = 0; qt2 < 2; ++qt2){
        u32 byte = (u32)((qt2 * 16 + lo) * 1024 + g * 64 + hi * 16);
        byte ^= (u32)(((g ^ lo) & 7) << 4);
        const bf16x8 af = *(const bf16x8*)((const char*)A2 + byte);
        #pragma unroll
        for (int nd = 0; nd < 4; ++nd)
          opv[g2][qt2][nd] = __builtin_amdgcn_mfma_f32_16x16x32_bf16(af, vb[g2][nd], opv[g2][qt2][nd], 0, 0, 0);
      }
    }
  }

  // epilogue: bf16 partial; rows q = q0 + qt2*16 + hi*4 + r, col = g*64 + nd*16 + lo
  u16* out = AOp + (size_t)grp * (2048 * 1024);
  #pragma unroll
  for (int g2 = 0; g2 < 2; ++g2){
    const int g = w + g2 * 8;
    #pragma unroll
    for (int qt2 = 0; qt2 < 2; ++qt2)
      #pragma unroll
      for (int nd = 0; nd < 4; ++nd)
        #pragma unroll
        for (int r = 0; r < 4; ++r)
          out[(size_t)(q0 + qt2 * 16 + hi * 4 + r) * 1024 + g * 64 + nd * 16 + lo] = f2b(opv[g2][qt2][nd][r]);
  }
}

// ---------------- V column sums (for bm term), fragment-linear layout ----------------
__global__ __launch_bounds__(256) void colsum_k(const u16* __restrict__ Vt, float* __restrict__ Vcs){
  const int rowd = blockIdx.x;                   // (bh)*64 + d
  const int bh = rowd >> 6, d = rowd & 63;
  const int nd = d >> 4, lo = d & 15;
  const int tid = threadIdx.x;
  const int k5 = tid >> 2, hi = tid & 3;         // 64 k5 x 4 hi = 256 threads, 8 k each
  const u16* p = Vt + (size_t)bh * 131072 + (size_t)k5 * 2048 + nd * 512 + hi * 128 + lo * 8;
  const ushort4 a = *(const ushort4*)&p[0];
  const ushort4 c = *(const ushort4*)&p[4];
  float s = b2f(a.x) + b2f(a.y) + b2f(a.z) + b2f(a.w) + b2f(c.x) + b2f(c.y) + b2f(c.z) + b2f(c.w);
  #pragma unroll
  for (int off = 1; off < 64; off <<= 1) s += __shfl_xor(s, off);
  __shared__ float red[4];
  if ((tid & 63) == 0) red[tid >> 6] = s;
  __syncthreads();
  if (tid == 0) Vcs[rowd] = red[0] + red[1] + red[2] + red[3];
}

// ---------------- residual + bm*colsum + sum of 4 bf16 partials + LayerNorm ----------------
__global__ __launch_bounds__(256) void ln_k(const u16* __restrict__ AOp, const float* __restrict__ qin,
    const float* __restrict__ bm, const float* __restrict__ Vcs,
    const float* __restrict__ gam, const float* __restrict__ bet, u16* __restrict__ XBo)
{
  const int row = blockIdx.x, b = row >> 11, seq = row & 2047, tid = threadIdx.x;
  const int c0 = tid * 4;
  const float4 qv = *(const float4*)&qin[(size_t)row * 1024 + c0];
  const int hh = c0 >> 6, dd = c0 & 63;
  const float bmv = bm[hh];
  const float* vc = Vcs + ((size_t)b * 16 + hh) * 64 + dd;
  float v[4];
  v[0] = qv.x + bmv * vc[0];
  v[1] = qv.y + bmv * vc[1];
  v[2] = qv.z + bmv * vc[2];
  v[3] = qv.w + bmv * vc[3];
  #pragma unroll
  for (int p = 0; p < 4; ++p){
    const ushort4 av = *(const ushort4*)&AOp[((size_t)(p * 2 + b) * 2048 + seq) * 1024 + c0];
    v[0] += b2f(av.x); v[1] += b2f(av.y); v[2] += b2f(av.z); v[3] += b2f(av.w);
  }
  float s1 = v[0] + v[1] + v[2] + v[3];
  float s2 = v[0]*v[0] + v[1]*v[1] + v[2]*v[2] + v[3]*v[3];
  #pragma unroll
  for (int off = 1; off < 64; off <<= 1){ s1 += __shfl_xor(s1, off); s2 += __shfl_xor(s2, off); }
  __shared__ float r1[4], r2[4];
  if ((tid & 63) == 0){ r1[tid >> 6] = s1; r2[tid >> 6] = s2; }
  __syncthreads();
  const float t1 = r1[0] + r1[1] + r1[2] + r1[3];
  const float t2 = r2[0] + r2[1] + r2[2] + r2[3];
  const float mean = t1 * (1.0f / 1024.0f);
  const float var  = t2 * (1.0f / 1024.0f) - mean * mean;
  const float inv  = rsqrtf(var + 1e-5f);
  ushort4 o;
  o.x = f2b((v[0] - mean) * inv * gam[c0 + 0] + bet[c0 + 0]);
  o.y = f2b((v[1] - mean) * inv * gam[c0 + 1] + bet[c0 + 1]);
  o.z = f2b((v[2] - mean) * inv * gam[c0 + 2] + bet[c0 + 2]);
  o.w = f2b((v[3] - mean) * inv * gam[c0 + 3] + bet[c0 + 3]);
  *(ushort4*)&XBo[(size_t)row * 1024 + c0] = o;
}

extern "C" void kernel_launch(void* const* d_in, const int* in_sizes, int n_in,
                              void* d_out, int out_size, void* d_ws, size_t ws_size,
                              hipStream_t stream) {
  const float* q   = (const float*)d_in[0];
  const float* Wq  = (const float*)d_in[1];
  const float* bq  = (const float*)d_in[2];
  const float* Wk  = (const float*)d_in[3];
  const float* bk  = (const float*)d_in[4];
  const float* Wv  = (const float*)d_in[5];
  const float* bv  = (const float*)d_in[6];
  const float* Wm  = (const float*)d_in[7];
  const float* bm  = (const float*)d_in[8];
  const float* W1  = (const float*)d_in[9];
  const float* b1  = (const float*)d_in[10];
  const float* W2  = (const float*)d_in[11];
  const float* b2  = (const float*)d_in[12];
  const float* lng = (const float*)d_in[13];
  const float* lnb = (const float*)d_in[14];

  char* ws = (char*)d_ws;
  const size_t MB = 1u << 20;
  u16*  XB  = (u16*)(ws);             // 8 MB  bf16 x / xb
  u16*  WB  = (u16*)(ws + 8  * MB);   // 6 MB  packed Wq|Wk|Wv
  u16*  Qb  = (u16*)(ws + 14 * MB);   // 8 MB  fragment-linear Q (pre-scaled by 1/8)
  u16*  Kb  = (u16*)(ws + 22 * MB);   // 8 MB  fragment-linear K (reused as Hb for FFN)
  u16*  Vt  = (u16*)(ws + 30 * MB);   // 8 MB  fragment-linear V
  float* ml = (float*)(ws + 38 * MB); // 0.25 MB [b][h][q] denom l
  float* Vcs= (float*)(ws + 39 * MB); // 8 KB
  u16*  AOp = (u16*)(ws + 40 * MB);   // 32 MB bf16 attention partials [grp=ks*2+b][2048][1024]
  u16*  WB2 = (u16*)(ws + 72 * MB);   // 4 MB  packed W1|W2
  u16*  Hb  = Kb;

  pack_x  <<<4096, 256, 0, stream>>>(q, XB);
  pack_wT5<<<dim3(256, 5), 256, 0, stream>>>(Wq, Wk, Wv, W1, W2, WB, WB2);

  gemm_qkv<<<dim3(32, 24), 256, 0, stream>>>(XB, WB, bq, bk, bv, Qb, Kb, Vt);

  attn_ml <<<1024, 256, 0, stream>>>(Qb, Kb, ml);
  colsum_k<<<2048, 256, 0, stream>>>(Vt, Vcs);

  attn_fused<<<dim3(8, 64), 512, 0, stream>>>(Qb, Kb, Vt, ml, Wm, AOp);

  ln_k<<<4096, 256, 0, stream>>>(AOp, q, bm, Vcs, lng, lnb, XB);

  gemm_bt64<1><<<dim3(64, 8), 256, 0, stream>>>(XB, WB2, b1, Hb, nullptr, nullptr);
  gemm_bt64<3><<<dim3(64, 8), 256, 0, stream>>>(Hb, WB2 + 1024 * 1024, b2, nullptr, XB, (float*)d_out);
}

// Round 21
// 228.063 us; speedup vs baseline: 1.0325x; 1.0325x over previous
//
#include <hip/hip_runtime.h>
#include <hip/hip_bf16.h>
#include <math.h>

typedef unsigned short u16;
typedef unsigned int u32;
typedef __attribute__((ext_vector_type(8))) short bf16x8;
typedef __attribute__((ext_vector_type(4))) float f32x4;

// float -> bf16 (RNE) via HIP native conversion (lowers to v_cvt_pk_bf16_f32)
__device__ __forceinline__ u16 f2b(float f){
  __hip_bfloat16 h = __float2bfloat16(f);
  u16 r;
  __builtin_memcpy(&r, &h, 2);
  return r;
}
__device__ __forceinline__ float b2f(u16 h){ return __uint_as_float(((u32)h) << 16); }

__device__ __forceinline__ void gll16(const void* g, void* l){
  __builtin_amdgcn_global_load_lds((const __attribute__((address_space(1))) void*)g,
                                   (__attribute__((address_space(3))) void*)l, 16, 0, 0);
}

// Fragment-linear layouts (bh = b*16+h), each 131072 u16 per bh:
//  Qf/Kf: idx = bh*131072 + (seq>>4)*1024 + (d>>3)*128 + (seq&15)*8 + (d&7)
//  Vf   : idx = bh*131072 + (k>>5)*2048 + (d>>4)*512 + ((k>>3)&3)*128 + (d&15)*8 + (k&7)
// Q stored PRE-SCALED by 0.125 (exact; bit-identical results).

// ---------------- pack kernels ----------------
__global__ __launch_bounds__(256) void pack_x(const float* __restrict__ in, u16* __restrict__ out){
  const int i = blockIdx.x * 256 + threadIdx.x;
  const float4 v = ((const float4*)in)[i];
  ushort4 o; o.x = f2b(v.x); o.y = f2b(v.y); o.z = f2b(v.z); o.w = f2b(v.w);
  ((ushort4*)out)[i] = o;
}

// batched coalesced transpose: 5 weights in one launch.
__global__ __launch_bounds__(256) void pack_wT5(
    const float* __restrict__ w0, const float* __restrict__ w1, const float* __restrict__ w2,
    const float* __restrict__ w3, const float* __restrict__ w4,
    u16* __restrict__ oqkv, u16* __restrict__ o12)
{
  __shared__ u16 t[64][68];
  const int sel = blockIdx.y;
  const float* in = (sel == 0) ? w0 : (sel == 1) ? w1 : (sel == 2) ? w2 : (sel == 3) ? w3 : w4;
  u16* out = (sel < 3) ? (oqkv + (size_t)sel * 1024 * 1024) : (o12 + (size_t)(sel - 3) * 1024 * 1024);
  const int k0 = (blockIdx.x & 15) * 64, n0 = (blockIdx.x >> 4) * 64;
  const int tx = threadIdx.x & 15, ty = threadIdx.x >> 4;
  #pragma unroll
  for (int j = 0; j < 4; ++j){
    const int r = ty + j * 16;
    const float4 v = *(const float4*)&in[(size_t)(k0 + r) * 1024 + n0 + tx * 4];
    t[tx*4+0][r] = f2b(v.x); t[tx*4+1][r] = f2b(v.y);
    t[tx*4+2][r] = f2b(v.z); t[tx*4+3][r] = f2b(v.w);
  }
  __syncthreads();
  #pragma unroll
  for (int j = 0; j < 4; ++j){
    const int c = ty + j * 16;
    *(ushort4*)&out[(size_t)(n0 + c) * 1024 + k0 + tx * 4] = *(const ushort4*)&t[c][tx * 4];
  }
}

// ---------------- 128x128 bf16 GEMM -- QKV projection, fragment-linear epilogue ----------------
__global__ __launch_bounds__(256) void gemm_qkv(
    const u16* __restrict__ A, const u16* __restrict__ Bt,
    const float* __restrict__ bias0, const float* __restrict__ bias1, const float* __restrict__ bias2,
    u16* __restrict__ o0, u16* __restrict__ o1, u16* __restrict__ o2)
{
  __shared__ __align__(16) u16 As[128 * 32];
  __shared__ __align__(16) u16 Bs[128 * 32];
  const int bm = blockIdx.x, bn = blockIdx.y;
  const int tid = threadIdx.x, w = tid >> 6, l = tid & 63;
  const int wm = (w >> 1) * 64, wn = (w & 1) * 64;
  const u16* Ab = A + (size_t)bm * 128 * 1024;
  const u16* Bb = Bt + (size_t)bn * 128 * 1024;
  const int srow = w * 16 + (l >> 2);
  const int scol = (l & 3) * 8;
  f32x4 acc[4][4];
  #pragma unroll
  for (int m = 0; m < 4; ++m)
    #pragma unroll
    for (int n = 0; n < 4; ++n) acc[m][n] = (f32x4){0.f, 0.f, 0.f, 0.f};
  for (int kt = 0; kt < 32; ++kt){
    const int k0 = kt << 5;
    #pragma unroll
    for (int j = 0; j < 2; ++j){
      gll16(Ab + (size_t)(j * 64 + srow) * 1024 + (k0 + scol), (char*)As + j * 4096 + w * 1024);
      gll16(Bb + (size_t)(j * 64 + srow) * 1024 + (k0 + scol), (char*)Bs + j * 4096 + w * 1024);
    }
    __syncthreads();
    bf16x8 af[4], bfr[4];
    #pragma unroll
    for (int m = 0; m < 4; ++m) af[m]  = *(const bf16x8*)&As[(wm + m * 16 + (l & 15)) * 32 + (l >> 4) * 8];
    #pragma unroll
    for (int n = 0; n < 4; ++n) bfr[n] = *(const bf16x8*)&Bs[(wn + n * 16 + (l & 15)) * 32 + (l >> 4) * 8];
    #pragma unroll
    for (int m = 0; m < 4; ++m)
      #pragma unroll
      for (int n = 0; n < 4; ++n)
        acc[m][n] = __builtin_amdgcn_mfma_f32_16x16x32_bf16(af[m], bfr[n], acc[m][n], 0, 0, 0);
    __syncthreads();
  }
  #pragma unroll
  for (int m = 0; m < 4; ++m){
    #pragma unroll
    for (int n = 0; n < 4; ++n){
      const int row0 = bm * 128 + wm + m * 16 + ((l >> 4) << 2);
      const int col  = bn * 128 + wn + n * 16 + (l & 15);
      const int sec = col >> 10, cw = col & 1023, hh = cw >> 6, d = cw & 63;
      const float bias = (sec == 0 ? bias0 : (sec == 1 ? bias1 : bias2))[cw];
      #pragma unroll
      for (int r = 0; r < 4; ++r){
        const int rr = row0 + r, bi = rr >> 11, seq = rr & 2047;
        const float v = acc[m][n][r] + bias;
        const size_t bhB = (size_t)(bi * 16 + hh) * 131072;
        if (sec < 2){
          const size_t idx = bhB + (size_t)(seq >> 4) * 1024 + (d >> 3) * 128 + (seq & 15) * 8 + (d & 7);
          (sec == 0 ? o0 : o1)[idx] = f2b(sec == 0 ? v * 0.125f : v);
        } else {
          const size_t idx = bhB + (size_t)(seq >> 5) * 2048 + (d >> 4) * 512 + ((seq >> 3) & 3) * 128 + (d & 15) * 8 + (seq & 7);
          o2[idx] = f2b(v);
        }
      }
    }
  }
}

// ---------------- 64x128 bf16 GEMM (K=1024), 2 blocks/CU for FFN ----------------
template<int EPI>
__global__ __launch_bounds__(256) void gemm_bt64(
    const u16* __restrict__ A, const u16* __restrict__ Bt,
    const float* __restrict__ bias0,
    u16* __restrict__ o0, const u16* __restrict__ res, float* __restrict__ fo)
{
  __shared__ __align__(16) u16 As[64 * 32];
  __shared__ __align__(16) u16 Bs[128 * 32];
  const int bm = blockIdx.x, bn = blockIdx.y;
  const int tid = threadIdx.x, w = tid >> 6, l = tid & 63;
  const int lo = l & 15, hi = l >> 4;
  const int wm = (w >> 1) * 32, wn = (w & 1) * 64;
  const u16* Ab = A + (size_t)bm * 64 * 1024;
  const u16* Bb = Bt + (size_t)bn * 128 * 1024;
  const int srow = w * 16 + (l >> 2);
  const int scol = (l & 3) * 8;
  f32x4 acc[2][4];
  #pragma unroll
  for (int m = 0; m < 2; ++m)
    #pragma unroll
    for (int n = 0; n < 4; ++n) acc[m][n] = (f32x4){0.f, 0.f, 0.f, 0.f};
  for (int kt = 0; kt < 32; ++kt){
    const int k0 = kt << 5;
    gll16(Ab + (size_t)srow * 1024 + (k0 + scol), (char*)As + w * 1024);
    #pragma unroll
    for (int j = 0; j < 2; ++j)
      gll16(Bb + (size_t)(j * 64 + srow) * 1024 + (k0 + scol), (char*)Bs + j * 4096 + w * 1024);
    __syncthreads();
    bf16x8 af[2], bfr[4];
    #pragma unroll
    for (int m = 0; m < 2; ++m) af[m]  = *(const bf16x8*)&As[(wm + m * 16 + lo) * 32 + hi * 8];
    #pragma unroll
    for (int n = 0; n < 4; ++n) bfr[n] = *(const bf16x8*)&Bs[(wn + n * 16 + lo) * 32 + hi * 8];
    #pragma unroll
    for (int m = 0; m < 2; ++m)
      #pragma unroll
      for (int n = 0; n < 4; ++n)
        acc[m][n] = __builtin_amdgcn_mfma_f32_16x16x32_bf16(af[m], bfr[n], acc[m][n], 0, 0, 0);
    __syncthreads();
  }
  #pragma unroll
  for (int m = 0; m < 2; ++m){
    #pragma unroll
    for (int n = 0; n < 4; ++n){
      const int row0 = bm * 64 + wm + m * 16 + hi * 4;
      const int col  = bn * 128 + wn + n * 16 + lo;
      const float bias = bias0[col];
      if (EPI == 1){
        #pragma unroll
        for (int r = 0; r < 4; ++r){
          const float v = acc[m][n][r] + bias;
          const float gv = 0.5f * v * (1.0f + erff(v * 0.70710678118654752f));
          o0[(size_t)(row0 + r) * 1024 + col] = f2b(gv);
        }
      } else {
        #pragma unroll
        for (int r = 0; r < 4; ++r){
          const float v = acc[m][n][r] + bias + b2f(res[(size_t)(row0 + r) * 1024 + col]);
          fo[(size_t)(row0 + r) * 1024 + col] = v;
        }
      }
    }
  }
}

// ---------------- attention pass 1: denom l only (no max; Q pre-scaled) ----------------
__global__ __launch_bounds__(256) void attn_ml(const u16* __restrict__ Qb, const u16* __restrict__ Kb,
                                               float* __restrict__ ml){
  const int qt = blockIdx.x & 31, bh = blockIdx.x >> 5;
  const int tid = threadIdx.x, w = tid >> 6, l = tid & 63;
  const int lo = l & 15, hi = l >> 4;
  const u16* Qh = Qb + (size_t)bh * 131072;
  const u16* Kh = Kb + (size_t)bh * 131072;
  const int q0 = qt * 64 + w * 16;
  const int s16q = q0 >> 4;
  const bf16x8 qb0 = *(const bf16x8*)&Qh[(size_t)s16q * 1024 + hi * 128 + lo * 8];
  const bf16x8 qb1 = *(const bf16x8*)&Qh[(size_t)s16q * 1024 + (hi + 4) * 128 + lo * 8];
  float l0 = 0.f, l1 = 0.f;
  for (int kt = 0; kt < 128; kt += 2){
    const bf16x8 ka0 = *(const bf16x8*)&Kh[(size_t)kt * 1024 + hi * 128 + lo * 8];
    const bf16x8 ka1 = *(const bf16x8*)&Kh[(size_t)kt * 1024 + (hi + 4) * 128 + lo * 8];
    const bf16x8 kb0 = *(const bf16x8*)&Kh[(size_t)(kt + 1) * 1024 + hi * 128 + lo * 8];
    const bf16x8 kb1 = *(const bf16x8*)&Kh[(size_t)(kt + 1) * 1024 + (hi + 4) * 128 + lo * 8];
    f32x4 s0 = (f32x4){0.f, 0.f, 0.f, 0.f}, s1 = (f32x4){0.f, 0.f, 0.f, 0.f};
    s0 = __builtin_amdgcn_mfma_f32_16x16x32_bf16(ka0, qb0, s0, 0, 0, 0);
    s0 = __builtin_amdgcn_mfma_f32_16x16x32_bf16(ka1, qb1, s0, 0, 0, 0);
    s1 = __builtin_amdgcn_mfma_f32_16x16x32_bf16(kb0, qb0, s1, 0, 0, 0);
    s1 = __builtin_amdgcn_mfma_f32_16x16x32_bf16(kb1, qb1, s1, 0, 0, 0);
    l0 += __expf(s0[0]) + __expf(s0[1]) + __expf(s0[2]) + __expf(s0[3]);
    l1 += __expf(s1[0]) + __expf(s1[1]) + __expf(s1[2]) + __expf(s1[3]);
  }
  float ls = l0 + l1;
  ls += __shfl_xor(ls, 16);
  ls += __shfl_xor(ls, 32);
  if (l < 16) ml[(size_t)bh * 2048 + q0 + l] = ls;
}

// ---------------- fused pass 2 v15: 16 waves x 1 head, QBLK=32, KS=4, fragment-linear ----------------
// grid = dim3(8, 64), 1024 threads. Wave w: phase A head w, phase B q-rows 2w..2w+1, phase C head w.
__global__ __launch_bounds__(1024) void attn_fused(
    const u16* __restrict__ Qb, const u16* __restrict__ Kb, const u16* __restrict__ Vt,
    const float* __restrict__ ml, const float* __restrict__ Wm, u16* __restrict__ AOp)
{
  __shared__ __align__(16) u16 P2[32 * 32 * 20 + 32];  // [q:32][k:32][h pad20] + guard
  __shared__ __align__(16) u16 A2[32 * 16 * 32];       // byte = q*1024+g*64+2k ^ ((g^q)&7)<<4
  const int grp = blockIdx.x, qt = blockIdx.y;
  const int b = grp & 1, ks = grp >> 1;
  const int tid = threadIdx.x, w = tid >> 6, l = tid & 63;
  const int lo = l & 15, hi = l >> 4;
  const int q0 = qt * 32;

  // zero P2 (pad/guard finite-zero)
  for (int i = tid; i < (32 * 32 * 20 + 32) / 8; i += 1024)
    ((uint4*)P2)[i] = (uint4){0u, 0u, 0u, 0u};

  const u16* Qh = Qb + (size_t)(b * 16 + w) * 131072;   // head w
  const u16* Kh = Kb + (size_t)(b * 16 + w) * 131072;
  const u16* Vg = Vt + (size_t)(b * 16 + w) * 131072;

  // Q fragments (head w): [qt2][half], rows q = q0 + qt2*16 + lo
  bf16x8 qa[2][2];
  #pragma unroll
  for (int qt2 = 0; qt2 < 2; ++qt2){
    const size_t s16 = (size_t)(qt * 2 + qt2) * 1024;
    qa[qt2][0] = *(const bf16x8*)&Qh[s16 + hi * 128 + lo * 8];
    qa[qt2][1] = *(const bf16x8*)&Qh[s16 + (hi + 4) * 128 + lo * 8];
  }

  // softmax inverse denominators (head w): [qt2][r] for rows q = q0 + qt2*16 + hi*4 + r
  float il_[2][4];
  #pragma unroll
  for (int qt2 = 0; qt2 < 2; ++qt2)
    #pragma unroll
    for (int r = 0; r < 4; ++r)
      il_[qt2][r] = 1.0f / ml[(size_t)(b * 16 + w) * 2048 + q0 + qt2 * 16 + hi * 4 + r];

  // Wm fragment: B-operand cols g = lo, contraction h = hi*8+i (zero for h>=16)
  bf16x8 wmf;
  #pragma unroll
  for (int i = 0; i < 8; ++i){
    const int hh = hi * 8 + i;
    wmf[i] = (hh < 16) ? (short)f2b(Wm[lo * 16 + hh]) : (short)0;
  }

  f32x4 opv[2][4];   // [qt2][nd] for output head g = w
  #pragma unroll
  for (int qt2 = 0; qt2 < 2; ++qt2)
    #pragma unroll
    for (int nd = 0; nd < 4; ++nd) opv[qt2][nd] = (f32x4){0.f, 0.f, 0.f, 0.f};

  __syncthreads();   // P2 zeroing done

  for (int kt = 0; kt < 16; ++kt){
    // ---- issue V loads early (head w) ----
    const size_t k5B = (size_t)(ks * 16 + kt) * 2048;
    bf16x8 vb[4];
    #pragma unroll
    for (int nd = 0; nd < 4; ++nd)
      vb[nd] = *(const bf16x8*)&Vg[k5B + nd * 512 + hi * 128 + lo * 8];
    // ---- phase A: QK^T + softmax for head w, 32 q rows, 32 k ----
    #pragma unroll
    for (int m = 0; m < 2; ++m){
      const size_t s16k = (size_t)(ks * 32 + kt * 2 + m) * 1024;
      bf16x8 kb0 = *(const bf16x8*)&Kh[s16k + hi * 128 + lo * 8];
      bf16x8 kb1 = *(const bf16x8*)&Kh[s16k + (hi + 4) * 128 + lo * 8];
      #pragma unroll
      for (int qt2 = 0; qt2 < 2; ++qt2){
        f32x4 s = (f32x4){0.f, 0.f, 0.f, 0.f};
        s = __builtin_amdgcn_mfma_f32_16x16x32_bf16(qa[qt2][0], kb0, s, 0, 0, 0);
        s = __builtin_amdgcn_mfma_f32_16x16x32_bf16(qa[qt2][1], kb1, s, 0, 0, 0);
        const int k_loc = m * 16 + lo;
        #pragma unroll
        for (int r = 0; r < 4; ++r){
          const float p = __expf(s[r]) * il_[qt2][r];
          const int q_loc = qt2 * 16 + hi * 4 + r;
          *(u16*)((char*)P2 + q_loc * 1280 + k_loc * 40 + w * 2) = f2b(p);
        }
      }
    }
    __syncthreads();   // P2 ready; previous-iter A2 reads complete
    // ---- phase B: talking-heads mix for q-rows 2w, 2w+1 ----
    #pragma unroll
    for (int qq = 0; qq < 2; ++qq){
      const int qr = w * 2 + qq;
      #pragma unroll
      for (int m = 0; m < 2; ++m){
        const bf16x8 pf = *(const bf16x8*)((const char*)P2 + qr * 1280 + (m * 16 + lo) * 40 + hi * 16);
        f32x4 a2 = (f32x4){0.f, 0.f, 0.f, 0.f};
        a2 = __builtin_amdgcn_mfma_f32_16x16x32_bf16(pf, wmf, a2, 0, 0, 0);
        ushort4 o4;
        o4.x = f2b(a2[0]); o4.y = f2b(a2[1]); o4.z = f2b(a2[2]); o4.w = f2b(a2[3]);
        u32 byte = (u32)(qr * 1024 + lo * 64 + m * 32 + hi * 8);
        byte ^= (u32)(((lo ^ qr) & 7) << 4);
        *(ushort4*)((char*)A2 + byte) = o4;
      }
    }
    __syncthreads();   // A2 ready
    // ---- phase C: PV for head g = w ----
    #pragma unroll
    for (int qt2 = 0; qt2 < 2; ++qt2){
      u32 byte = (u32)((qt2 * 16 + lo) * 1024 + w * 64 + hi * 16);
      byte ^= (u32)(((w ^ lo) & 7) << 4);
      const bf16x8 af = *(const bf16x8*)((const char*)A2 + byte);
      #pragma unroll
      for (int nd = 0; nd < 4; ++nd)
        opv[qt2][nd] = __builtin_amdgcn_mfma_f32_16x16x32_bf16(af, vb[nd], opv[qt2][nd], 0, 0, 0);
    }
  }

  // epilogue: bf16 partial; rows q = q0 + qt2*16 + hi*4 + r, col = w*64 + nd*16 + lo
  u16* out = AOp + (size_t)grp * (2048 * 1024);
  #pragma unroll
  for (int qt2 = 0; qt2 < 2; ++qt2)
    #pragma unroll
    for (int nd = 0; nd < 4; ++nd)
      #pragma unroll
      for (int r = 0; r < 4; ++r)
        out[(size_t)(q0 + qt2 * 16 + hi * 4 + r) * 1024 + w * 64 + nd * 16 + lo] = f2b(opv[qt2][nd][r]);
}

// ---------------- V column sums (for bm term), fragment-linear layout ----------------
__global__ __launch_bounds__(256) void colsum_k(const u16* __restrict__ Vt, float* __restrict__ Vcs){
  const int rowd = blockIdx.x;                   // (bh)*64 + d
  const int bh = rowd >> 6, d = rowd & 63;
  const int nd = d >> 4, lo = d & 15;
  const int tid = threadIdx.x;
  const int k5 = tid >> 2, hi = tid & 3;         // 64 k5 x 4 hi = 256 threads, 8 k each
  const u16* p = Vt + (size_t)bh * 131072 + (size_t)k5 * 2048 + nd * 512 + hi * 128 + lo * 8;
  const ushort4 a = *(const ushort4*)&p[0];
  const ushort4 c = *(const ushort4*)&p[4];
  float s = b2f(a.x) + b2f(a.y) + b2f(a.z) + b2f(a.w) + b2f(c.x) + b2f(c.y) + b2f(c.z) + b2f(c.w);
  #pragma unroll
  for (int off = 1; off < 64; off <<= 1) s += __shfl_xor(s, off);
  __shared__ float red[4];
  if ((tid & 63) == 0) red[tid >> 6] = s;
  __syncthreads();
  if (tid == 0) Vcs[rowd] = red[0] + red[1] + red[2] + red[3];
}

// ---------------- residual + bm*colsum + sum of 4 bf16 partials + LayerNorm ----------------
__global__ __launch_bounds__(256) void ln_k(const u16* __restrict__ AOp, const float* __restrict__ qin,
    const float* __restrict__ bm, const float* __restrict__ Vcs,
    const float* __restrict__ gam, const float* __restrict__ bet, u16* __restrict__ XBo)
{
  const int row = blockIdx.x, b = row >> 11, seq = row & 2047, tid = threadIdx.x;
  const int c0 = tid * 4;
  const float4 qv = *(const float4*)&qin[(size_t)row * 1024 + c0];
  const int hh = c0 >> 6, dd = c0 & 63;
  const float bmv = bm[hh];
  const float* vc = Vcs + ((size_t)b * 16 + hh) * 64 + dd;
  float v[4];
  v[0] = qv.x + bmv * vc[0];
  v[1] = qv.y + bmv * vc[1];
  v[2] = qv.z + bmv * vc[2];
  v[3] = qv.w + bmv * vc[3];
  #pragma unroll
  for (int p = 0; p < 4; ++p){
    const ushort4 av = *(const ushort4*)&AOp[((size_t)(p * 2 + b) * 2048 + seq) * 1024 + c0];
    v[0] += b2f(av.x); v[1] += b2f(av.y); v[2] += b2f(av.z); v[3] += b2f(av.w);
  }
  float s1 = v[0] + v[1] + v[2] + v[3];
  float s2 = v[0]*v[0] + v[1]*v[1] + v[2]*v[2] + v[3]*v[3];
  #pragma unroll
  for (int off = 1; off < 64; off <<= 1){ s1 += __shfl_xor(s1, off); s2 += __shfl_xor(s2, off); }
  __shared__ float r1[4], r2[4];
  if ((tid & 63) == 0){ r1[tid >> 6] = s1; r2[tid >> 6] = s2; }
  __syncthreads();
  const float t1 = r1[0] + r1[1] + r1[2] + r1[3];
  const float t2 = r2[0] + r2[1] + r2[2] + r2[3];
  const float mean = t1 * (1.0f / 1024.0f);
  const float var  = t2 * (1.0f / 1024.0f) - mean * mean;
  const float inv  = rsqrtf(var + 1e-5f);
  ushort4 o;
  o.x = f2b((v[0] - mean) * inv * gam[c0 + 0] + bet[c0 + 0]);
  o.y = f2b((v[1] - mean) * inv * gam[c0 + 1] + bet[c0 + 1]);
  o.z = f2b((v[2] - mean) * inv * gam[c0 + 2] + bet[c0 + 2]);
  o.w = f2b((v[3] - mean) * inv * gam[c0 + 3] + bet[c0 + 3]);
  *(ushort4*)&XBo[(size_t)row * 1024 + c0] = o;
}

extern "C" void kernel_launch(void* const* d_in, const int* in_sizes, int n_in,
                              void* d_out, int out_size, void* d_ws, size_t ws_size,
                              hipStream_t stream) {
  const float* q   = (const float*)d_in[0];
  const float* Wq  = (const float*)d_in[1];
  const float* bq  = (const float*)d_in[2];
  const float* Wk  = (const float*)d_in[3];
  const float* bk  = (const float*)d_in[4];
  const float* Wv  = (const float*)d_in[5];
  const float* bv  = (const float*)d_in[6];
  const float* Wm  = (const float*)d_in[7];
  const float* bm  = (const float*)d_in[8];
  const float* W1  = (const float*)d_in[9];
  const float* b1  = (const float*)d_in[10];
  const float* W2  = (const float*)d_in[11];
  const float* b2  = (const float*)d_in[12];
  const float* lng = (const float*)d_in[13];
  const float* lnb = (const float*)d_in[14];

  char* ws = (char*)d_ws;
  const size_t MB = 1u << 20;
  u16*  XB  = (u16*)(ws);             // 8 MB  bf16 x / xb
  u16*  WB  = (u16*)(ws + 8  * MB);   // 6 MB  packed Wq|Wk|Wv
  u16*  Qb  = (u16*)(ws + 14 * MB);   // 8 MB  fragment-linear Q (pre-scaled by 1/8)
  u16*  Kb  = (u16*)(ws + 22 * MB);   // 8 MB  fragment-linear K (reused as Hb for FFN)
  u16*  Vt  = (u16*)(ws + 30 * MB);   // 8 MB  fragment-linear V
  float* ml = (float*)(ws + 38 * MB); // 0.25 MB [b][h][q] denom l
  float* Vcs= (float*)(ws + 39 * MB); // 8 KB
  u16*  AOp = (u16*)(ws + 40 * MB);   // 32 MB bf16 attention partials [grp=ks*2+b][2048][1024]
  u16*  WB2 = (u16*)(ws + 72 * MB);   // 4 MB  packed W1|W2
  u16*  Hb  = Kb;

  pack_x  <<<4096, 256, 0, stream>>>(q, XB);
  pack_wT5<<<dim3(256, 5), 256, 0, stream>>>(Wq, Wk, Wv, W1, W2, WB, WB2);

  gemm_qkv<<<dim3(32, 24), 256, 0, stream>>>(XB, WB, bq, bk, bv, Qb, Kb, Vt);

  attn_ml <<<1024, 256, 0, stream>>>(Qb, Kb, ml);
  colsum_k<<<2048, 256, 0, stream>>>(Vt, Vcs);

  attn_fused<<<dim3(8, 64), 1024, 0, stream>>>(Qb, Kb, Vt, ml, Wm, AOp);

  ln_k<<<4096, 256, 0, stream>>>(AOp, q, bm, Vcs, lng, lnb, XB);

  gemm_bt64<1><<<dim3(64, 8), 256, 0, stream>>>(XB, WB2, b1, Hb, nullptr, nullptr);
  gemm_bt64<3><<<dim3(64, 8), 256, 0, stream>>>(Hb, WB2 + 1024 * 1024, b2, nullptr, XB, (float*)d_out);
}

// Round 22
// 223.579 us; speedup vs baseline: 1.0532x; 1.0201x over previous
//
#include <hip/hip_runtime.h>
#include <hip/hip_bf16.h>
#include <math.h>

typedef unsigned short u16;
typedef unsigned int u32;
typedef __attribute__((ext_vector_type(8))) short bf16x8;
typedef __attribute__((ext_vector_type(4))) float f32x4;

// float -> bf16 (RNE) via HIP native conversion (lowers to v_cvt_pk_bf16_f32)
__device__ __forceinline__ u16 f2b(float f){
  __hip_bfloat16 h = __float2bfloat16(f);
  u16 r;
  __builtin_memcpy(&r, &h, 2);
  return r;
}
__device__ __forceinline__ float b2f(u16 h){ return __uint_as_float(((u32)h) << 16); }

__device__ __forceinline__ void gll16(const void* g, void* l){
  __builtin_amdgcn_global_load_lds((const __attribute__((address_space(1))) void*)g,
                                   (__attribute__((address_space(3))) void*)l, 16, 0, 0);
}

// Fragment-linear layouts (bh = b*16+h), each 131072 u16 per bh:
//  Qf/Kf: idx = bh*131072 + (seq>>4)*1024 + (d>>3)*128 + (seq&15)*8 + (d&7)
//  Vf   : idx = bh*131072 + (k>>5)*2048 + (d>>4)*512 + ((k>>3)&3)*128 + (d&15)*8 + (k&7)
// Q stored PRE-SCALED by 0.125 (exact; bit-identical results).

// ---------------- pack kernels ----------------
__global__ __launch_bounds__(256) void pack_x(const float* __restrict__ in, u16* __restrict__ out){
  const int i = blockIdx.x * 256 + threadIdx.x;
  const float4 v = ((const float4*)in)[i];
  ushort4 o; o.x = f2b(v.x); o.y = f2b(v.y); o.z = f2b(v.z); o.w = f2b(v.w);
  ((ushort4*)out)[i] = o;
}

// batched coalesced transpose: 5 weights in one launch.
__global__ __launch_bounds__(256) void pack_wT5(
    const float* __restrict__ w0, const float* __restrict__ w1, const float* __restrict__ w2,
    const float* __restrict__ w3, const float* __restrict__ w4,
    u16* __restrict__ oqkv, u16* __restrict__ o12)
{
  __shared__ u16 t[64][68];
  const int sel = blockIdx.y;
  const float* in = (sel == 0) ? w0 : (sel == 1) ? w1 : (sel == 2) ? w2 : (sel == 3) ? w3 : w4;
  u16* out = (sel < 3) ? (oqkv + (size_t)sel * 1024 * 1024) : (o12 + (size_t)(sel - 3) * 1024 * 1024);
  const int k0 = (blockIdx.x & 15) * 64, n0 = (blockIdx.x >> 4) * 64;
  const int tx = threadIdx.x & 15, ty = threadIdx.x >> 4;
  #pragma unroll
  for (int j = 0; j < 4; ++j){
    const int r = ty + j * 16;
    const float4 v = *(const float4*)&in[(size_t)(k0 + r) * 1024 + n0 + tx * 4];
    t[tx*4+0][r] = f2b(v.x); t[tx*4+1][r] = f2b(v.y);
    t[tx*4+2][r] = f2b(v.z); t[tx*4+3][r] = f2b(v.w);
  }
  __syncthreads();
  #pragma unroll
  for (int j = 0; j < 4; ++j){
    const int c = ty + j * 16;
    *(ushort4*)&out[(size_t)(n0 + c) * 1024 + k0 + tx * 4] = *(const ushort4*)&t[c][tx * 4];
  }
}

// ---------------- 128x128 bf16 GEMM -- QKV projection, fragment-linear epilogue ----------------
__global__ __launch_bounds__(256) void gemm_qkv(
    const u16* __restrict__ A, const u16* __restrict__ Bt,
    const float* __restrict__ bias0, const float* __restrict__ bias1, const float* __restrict__ bias2,
    u16* __restrict__ o0, u16* __restrict__ o1, u16* __restrict__ o2)
{
  __shared__ __align__(16) u16 As[128 * 32];
  __shared__ __align__(16) u16 Bs[128 * 32];
  const int bm = blockIdx.x, bn = blockIdx.y;
  const int tid = threadIdx.x, w = tid >> 6, l = tid & 63;
  const int wm = (w >> 1) * 64, wn = (w & 1) * 64;
  const u16* Ab = A + (size_t)bm * 128 * 1024;
  const u16* Bb = Bt + (size_t)bn * 128 * 1024;
  const int srow = w * 16 + (l >> 2);
  const int scol = (l & 3) * 8;
  f32x4 acc[4][4];
  #pragma unroll
  for (int m = 0; m < 4; ++m)
    #pragma unroll
    for (int n = 0; n < 4; ++n) acc[m][n] = (f32x4){0.f, 0.f, 0.f, 0.f};
  for (int kt = 0; kt < 32; ++kt){
    const int k0 = kt << 5;
    #pragma unroll
    for (int j = 0; j < 2; ++j){
      gll16(Ab + (size_t)(j * 64 + srow) * 1024 + (k0 + scol), (char*)As + j * 4096 + w * 1024);
      gll16(Bb + (size_t)(j * 64 + srow) * 1024 + (k0 + scol), (char*)Bs + j * 4096 + w * 1024);
    }
    __syncthreads();
    bf16x8 af[4], bfr[4];
    #pragma unroll
    for (int m = 0; m < 4; ++m) af[m]  = *(const bf16x8*)&As[(wm + m * 16 + (l & 15)) * 32 + (l >> 4) * 8];
    #pragma unroll
    for (int n = 0; n < 4; ++n) bfr[n] = *(const bf16x8*)&Bs[(wn + n * 16 + (l & 15)) * 32 + (l >> 4) * 8];
    #pragma unroll
    for (int m = 0; m < 4; ++m)
      #pragma unroll
      for (int n = 0; n < 4; ++n)
        acc[m][n] = __builtin_amdgcn_mfma_f32_16x16x32_bf16(af[m], bfr[n], acc[m][n], 0, 0, 0);
    __syncthreads();
  }
  #pragma unroll
  for (int m = 0; m < 4; ++m){
    #pragma unroll
    for (int n = 0; n < 4; ++n){
      const int row0 = bm * 128 + wm + m * 16 + ((l >> 4) << 2);
      const int col  = bn * 128 + wn + n * 16 + (l & 15);
      const int sec = col >> 10, cw = col & 1023, hh = cw >> 6, d = cw & 63;
      const float bias = (sec == 0 ? bias0 : (sec == 1 ? bias1 : bias2))[cw];
      #pragma unroll
      for (int r = 0; r < 4; ++r){
        const int rr = row0 + r, bi = rr >> 11, seq = rr & 2047;
        const float v = acc[m][n][r] + bias;
        const size_t bhB = (size_t)(bi * 16 + hh) * 131072;
        if (sec < 2){
          const size_t idx = bhB + (size_t)(seq >> 4) * 1024 + (d >> 3) * 128 + (seq & 15) * 8 + (d & 7);
          (sec == 0 ? o0 : o1)[idx] = f2b(sec == 0 ? v * 0.125f : v);
        } else {
          const size_t idx = bhB + (size_t)(seq >> 5) * 2048 + (d >> 4) * 512 + ((seq >> 3) & 3) * 128 + (d & 15) * 8 + (seq & 7);
          o2[idx] = f2b(v);
        }
      }
    }
  }
}

// ---------------- 64x64 bf16 GEMM (K=1024), 4 blocks/CU for FFN ----------------
// EPI 1: bias+gelu -> o0 (bf16). EPI 3: bias + bf16 residual -> fo (f32).
template<int EPI>
__global__ __launch_bounds__(256) void gemm_bt64(
    const u16* __restrict__ A, const u16* __restrict__ Bt,
    const float* __restrict__ bias0,
    u16* __restrict__ o0, const u16* __restrict__ res, float* __restrict__ fo)
{
  __shared__ __align__(16) u16 As[64 * 32];
  __shared__ __align__(16) u16 Bs[64 * 32];
  const int bm = blockIdx.x, bn = blockIdx.y;
  const int tid = threadIdx.x, w = tid >> 6, l = tid & 63;
  const int lo = l & 15, hi = l >> 4;
  const int wm = (w >> 1) * 32, wn = (w & 1) * 32;
  const u16* Ab = A + (size_t)bm * 64 * 1024;
  const u16* Bb = Bt + (size_t)bn * 64 * 1024;
  const int srow = w * 16 + (l >> 2);
  const int scol = (l & 3) * 8;
  f32x4 acc[2][2];
  #pragma unroll
  for (int m = 0; m < 2; ++m)
    #pragma unroll
    for (int n = 0; n < 2; ++n) acc[m][n] = (f32x4){0.f, 0.f, 0.f, 0.f};
  for (int kt = 0; kt < 32; ++kt){
    const int k0 = kt << 5;
    gll16(Ab + (size_t)srow * 1024 + (k0 + scol), (char*)As + w * 1024);
    gll16(Bb + (size_t)srow * 1024 + (k0 + scol), (char*)Bs + w * 1024);
    __syncthreads();
    bf16x8 af[2], bfr[2];
    #pragma unroll
    for (int m = 0; m < 2; ++m) af[m]  = *(const bf16x8*)&As[(wm + m * 16 + lo) * 32 + hi * 8];
    #pragma unroll
    for (int n = 0; n < 2; ++n) bfr[n] = *(const bf16x8*)&Bs[(wn + n * 16 + lo) * 32 + hi * 8];
    #pragma unroll
    for (int m = 0; m < 2; ++m)
      #pragma unroll
      for (int n = 0; n < 2; ++n)
        acc[m][n] = __builtin_amdgcn_mfma_f32_16x16x32_bf16(af[m], bfr[n], acc[m][n], 0, 0, 0);
    __syncthreads();
  }
  #pragma unroll
  for (int m = 0; m < 2; ++m){
    #pragma unroll
    for (int n = 0; n < 2; ++n){
      const int row0 = bm * 64 + wm + m * 16 + hi * 4;
      const int col  = bn * 64 + wn + n * 16 + lo;
      const float bias = bias0[col];
      if (EPI == 1){
        #pragma unroll
        for (int r = 0; r < 4; ++r){
          const float v = acc[m][n][r] + bias;
          const float gv = 0.5f * v * (1.0f + erff(v * 0.70710678118654752f));
          o0[(size_t)(row0 + r) * 1024 + col] = f2b(gv);
        }
      } else {
        #pragma unroll
        for (int r = 0; r < 4; ++r){
          const float v = acc[m][n][r] + bias + b2f(res[(size_t)(row0 + r) * 1024 + col]);
          fo[(size_t)(row0 + r) * 1024 + col] = v;
        }
      }
    }
  }
}

// ---------------- attention pass 1: denom l only (no max; Q pre-scaled) ----------------
__global__ __launch_bounds__(256) void attn_ml(const u16* __restrict__ Qb, const u16* __restrict__ Kb,
                                               float* __restrict__ ml){
  const int qt = blockIdx.x & 31, bh = blockIdx.x >> 5;
  const int tid = threadIdx.x, w = tid >> 6, l = tid & 63;
  const int lo = l & 15, hi = l >> 4;
  const u16* Qh = Qb + (size_t)bh * 131072;
  const u16* Kh = Kb + (size_t)bh * 131072;
  const int q0 = qt * 64 + w * 16;
  const int s16q = q0 >> 4;
  const bf16x8 qb0 = *(const bf16x8*)&Qh[(size_t)s16q * 1024 + hi * 128 + lo * 8];
  const bf16x8 qb1 = *(const bf16x8*)&Qh[(size_t)s16q * 1024 + (hi + 4) * 128 + lo * 8];
  float l0 = 0.f, l1 = 0.f;
  for (int kt = 0; kt < 128; kt += 2){
    const bf16x8 ka0 = *(const bf16x8*)&Kh[(size_t)kt * 1024 + hi * 128 + lo * 8];
    const bf16x8 ka1 = *(const bf16x8*)&Kh[(size_t)kt * 1024 + (hi + 4) * 128 + lo * 8];
    const bf16x8 kb0 = *(const bf16x8*)&Kh[(size_t)(kt + 1) * 1024 + hi * 128 + lo * 8];
    const bf16x8 kb1 = *(const bf16x8*)&Kh[(size_t)(kt + 1) * 1024 + (hi + 4) * 128 + lo * 8];
    f32x4 s0 = (f32x4){0.f, 0.f, 0.f, 0.f}, s1 = (f32x4){0.f, 0.f, 0.f, 0.f};
    s0 = __builtin_amdgcn_mfma_f32_16x16x32_bf16(ka0, qb0, s0, 0, 0, 0);
    s0 = __builtin_amdgcn_mfma_f32_16x16x32_bf16(ka1, qb1, s0, 0, 0, 0);
    s1 = __builtin_amdgcn_mfma_f32_16x16x32_bf16(kb0, qb0, s1, 0, 0, 0);
    s1 = __builtin_amdgcn_mfma_f32_16x16x32_bf16(kb1, qb1, s1, 0, 0, 0);
    l0 += __expf(s0[0]) + __expf(s0[1]) + __expf(s0[2]) + __expf(s0[3]);
    l1 += __expf(s1[0]) + __expf(s1[1]) + __expf(s1[2]) + __expf(s1[3]);
  }
  float ls = l0 + l1;
  ls += __shfl_xor(ls, 16);
  ls += __shfl_xor(ls, 32);
  if (l < 16) ml[(size_t)bh * 2048 + q0 + l] = ls;
}

// ---------------- fused pass 2 v15: 16 waves x 1 head, QBLK=32, KS=4, fragment-linear ----------------
// grid = dim3(8, 64), 1024 threads. Wave w: phase A head w, phase B q-rows 2w..2w+1, phase C head w.
__global__ __launch_bounds__(1024) void attn_fused(
    const u16* __restrict__ Qb, const u16* __restrict__ Kb, const u16* __restrict__ Vt,
    const float* __restrict__ ml, const float* __restrict__ Wm, u16* __restrict__ AOp)
{
  __shared__ __align__(16) u16 P2[32 * 32 * 20 + 32];  // [q:32][k:32][h pad20] + guard
  __shared__ __align__(16) u16 A2[32 * 16 * 32];       // byte = q*1024+g*64+2k ^ ((g^q)&7)<<4
  const int grp = blockIdx.x, qt = blockIdx.y;
  const int b = grp & 1, ks = grp >> 1;
  const int tid = threadIdx.x, w = tid >> 6, l = tid & 63;
  const int lo = l & 15, hi = l >> 4;
  const int q0 = qt * 32;

  // zero P2 (pad/guard finite-zero)
  for (int i = tid; i < (32 * 32 * 20 + 32) / 8; i += 1024)
    ((uint4*)P2)[i] = (uint4){0u, 0u, 0u, 0u};

  const u16* Qh = Qb + (size_t)(b * 16 + w) * 131072;   // head w
  const u16* Kh = Kb + (size_t)(b * 16 + w) * 131072;
  const u16* Vg = Vt + (size_t)(b * 16 + w) * 131072;

  // Q fragments (head w): [qt2][half], rows q = q0 + qt2*16 + lo
  bf16x8 qa[2][2];
  #pragma unroll
  for (int qt2 = 0; qt2 < 2; ++qt2){
    const size_t s16 = (size_t)(qt * 2 + qt2) * 1024;
    qa[qt2][0] = *(const bf16x8*)&Qh[s16 + hi * 128 + lo * 8];
    qa[qt2][1] = *(const bf16x8*)&Qh[s16 + (hi + 4) * 128 + lo * 8];
  }

  // softmax inverse denominators (head w): [qt2][r] for rows q = q0 + qt2*16 + hi*4 + r
  float il_[2][4];
  #pragma unroll
  for (int qt2 = 0; qt2 < 2; ++qt2)
    #pragma unroll
    for (int r = 0; r < 4; ++r)
      il_[qt2][r] = 1.0f / ml[(size_t)(b * 16 + w) * 2048 + q0 + qt2 * 16 + hi * 4 + r];

  // Wm fragment: B-operand cols g = lo, contraction h = hi*8+i (zero for h>=16)
  bf16x8 wmf;
  #pragma unroll
  for (int i = 0; i < 8; ++i){
    const int hh = hi * 8 + i;
    wmf[i] = (hh < 16) ? (short)f2b(Wm[lo * 16 + hh]) : (short)0;
  }

  f32x4 opv[2][4];   // [qt2][nd] for output head g = w
  #pragma unroll
  for (int qt2 = 0; qt2 < 2; ++qt2)
    #pragma unroll
    for (int nd = 0; nd < 4; ++nd) opv[qt2][nd] = (f32x4){0.f, 0.f, 0.f, 0.f};

  __syncthreads();   // P2 zeroing done

  for (int kt = 0; kt < 16; ++kt){
    // ---- issue V loads early (head w) ----
    const size_t k5B = (size_t)(ks * 16 + kt) * 2048;
    bf16x8 vb[4];
    #pragma unroll
    for (int nd = 0; nd < 4; ++nd)
      vb[nd] = *(const bf16x8*)&Vg[k5B + nd * 512 + hi * 128 + lo * 8];
    // ---- phase A: QK^T + softmax for head w, 32 q rows, 32 k ----
    #pragma unroll
    for (int m = 0; m < 2; ++m){
      const size_t s16k = (size_t)(ks * 32 + kt * 2 + m) * 1024;
      bf16x8 kb0 = *(const bf16x8*)&Kh[s16k + hi * 128 + lo * 8];
      bf16x8 kb1 = *(const bf16x8*)&Kh[s16k + (hi + 4) * 128 + lo * 8];
      #pragma unroll
      for (int qt2 = 0; qt2 < 2; ++qt2){
        f32x4 s = (f32x4){0.f, 0.f, 0.f, 0.f};
        s = __builtin_amdgcn_mfma_f32_16x16x32_bf16(qa[qt2][0], kb0, s, 0, 0, 0);
        s = __builtin_amdgcn_mfma_f32_16x16x32_bf16(qa[qt2][1], kb1, s, 0, 0, 0);
        const int k_loc = m * 16 + lo;
        #pragma unroll
        for (int r = 0; r < 4; ++r){
          const float p = __expf(s[r]) * il_[qt2][r];
          const int q_loc = qt2 * 16 + hi * 4 + r;
          *(u16*)((char*)P2 + q_loc * 1280 + k_loc * 40 + w * 2) = f2b(p);
        }
      }
    }
    __syncthreads();   // P2 ready; previous-iter A2 reads complete
    // ---- phase B: talking-heads mix for q-rows 2w, 2w+1 ----
    #pragma unroll
    for (int qq = 0; qq < 2; ++qq){
      const int qr = w * 2 + qq;
      #pragma unroll
      for (int m = 0; m < 2; ++m){
        const bf16x8 pf = *(const bf16x8*)((const char*)P2 + qr * 1280 + (m * 16 + lo) * 40 + hi * 16);
        f32x4 a2 = (f32x4){0.f, 0.f, 0.f, 0.f};
        a2 = __builtin_amdgcn_mfma_f32_16x16x32_bf16(pf, wmf, a2, 0, 0, 0);
        ushort4 o4;
        o4.x = f2b(a2[0]); o4.y = f2b(a2[1]); o4.z = f2b(a2[2]); o4.w = f2b(a2[3]);
        u32 byte = (u32)(qr * 1024 + lo * 64 + m * 32 + hi * 8);
        byte ^= (u32)(((lo ^ qr) & 7) << 4);
        *(ushort4*)((char*)A2 + byte) = o4;
      }
    }
    __syncthreads();   // A2 ready
    // ---- phase C: PV for head g = w ----
    #pragma unroll
    for (int qt2 = 0; qt2 < 2; ++qt2){
      u32 byte = (u32)((qt2 * 16 + lo) * 1024 + w * 64 + hi * 16);
      byte ^= (u32)(((w ^ lo) & 7) << 4);
      const bf16x8 af = *(const bf16x8*)((const char*)A2 + byte);
      #pragma unroll
      for (int nd = 0; nd < 4; ++nd)
        opv[qt2][nd] = __builtin_amdgcn_mfma_f32_16x16x32_bf16(af, vb[nd], opv[qt2][nd], 0, 0, 0);
    }
  }

  // epilogue: bf16 partial; rows q = q0 + qt2*16 + hi*4 + r, col = w*64 + nd*16 + lo
  u16* out = AOp + (size_t)grp * (2048 * 1024);
  #pragma unroll
  for (int qt2 = 0; qt2 < 2; ++qt2)
    #pragma unroll
    for (int nd = 0; nd < 4; ++nd)
      #pragma unroll
      for (int r = 0; r < 4; ++r)
        out[(size_t)(q0 + qt2 * 16 + hi * 4 + r) * 1024 + w * 64 + nd * 16 + lo] = f2b(opv[qt2][nd][r]);
}

// ---------------- V column sums (for bm term), fragment-linear layout ----------------
__global__ __launch_bounds__(256) void colsum_k(const u16* __restrict__ Vt, float* __restrict__ Vcs){
  const int rowd = blockIdx.x;                   // (bh)*64 + d
  const int bh = rowd >> 6, d = rowd & 63;
  const int nd = d >> 4, lo = d & 15;
  const int tid = threadIdx.x;
  const int k5 = tid >> 2, hi = tid & 3;         // 64 k5 x 4 hi = 256 threads, 8 k each
  const u16* p = Vt + (size_t)bh * 131072 + (size_t)k5 * 2048 + nd * 512 + hi * 128 + lo * 8;
  const ushort4 a = *(const ushort4*)&p[0];
  const ushort4 c = *(const ushort4*)&p[4];
  float s = b2f(a.x) + b2f(a.y) + b2f(a.z) + b2f(a.w) + b2f(c.x) + b2f(c.y) + b2f(c.z) + b2f(c.w);
  #pragma unroll
  for (int off = 1; off < 64; off <<= 1) s += __shfl_xor(s, off);
  __shared__ float red[4];
  if ((tid & 63) == 0) red[tid >> 6] = s;
  __syncthreads();
  if (tid == 0) Vcs[rowd] = red[0] + red[1] + red[2] + red[3];
}

// ---------------- residual + bm*colsum + sum of 4 bf16 partials + LayerNorm ----------------
__global__ __launch_bounds__(256) void ln_k(const u16* __restrict__ AOp, const float* __restrict__ qin,
    const float* __restrict__ bm, const float* __restrict__ Vcs,
    const float* __restrict__ gam, const float* __restrict__ bet, u16* __restrict__ XBo)
{
  const int row = blockIdx.x, b = row >> 11, seq = row & 2047, tid = threadIdx.x;
  const int c0 = tid * 4;
  const float4 qv = *(const float4*)&qin[(size_t)row * 1024 + c0];
  const int hh = c0 >> 6, dd = c0 & 63;
  const float bmv = bm[hh];
  const float* vc = Vcs + ((size_t)b * 16 + hh) * 64 + dd;
  float v[4];
  v[0] = qv.x + bmv * vc[0];
  v[1] = qv.y + bmv * vc[1];
  v[2] = qv.z + bmv * vc[2];
  v[3] = qv.w + bmv * vc[3];
  #pragma unroll
  for (int p = 0; p < 4; ++p){
    const ushort4 av = *(const ushort4*)&AOp[((size_t)(p * 2 + b) * 2048 + seq) * 1024 + c0];
    v[0] += b2f(av.x); v[1] += b2f(av.y); v[2] += b2f(av.z); v[3] += b2f(av.w);
  }
  float s1 = v[0] + v[1] + v[2] + v[3];
  float s2 = v[0]*v[0] + v[1]*v[1] + v[2]*v[2] + v[3]*v[3];
  #pragma unroll
  for (int off = 1; off < 64; off <<= 1){ s1 += __shfl_xor(s1, off); s2 += __shfl_xor(s2, off); }
  __shared__ float r1[4], r2[4];
  if ((tid & 63) == 0){ r1[tid >> 6] = s1; r2[tid >> 6] = s2; }
  __syncthreads();
  const float t1 = r1[0] + r1[1] + r1[2] + r1[3];
  const float t2 = r2[0] + r2[1] + r2[2] + r2[3];
  const float mean = t1 * (1.0f / 1024.0f);
  const float var  = t2 * (1.0f / 1024.0f) - mean * mean;
  const float inv  = rsqrtf(var + 1e-5f);
  ushort4 o;
  o.x = f2b((v[0] - mean) * inv * gam[c0 + 0] + bet[c0 + 0]);
  o.y = f2b((v[1] - mean) * inv * gam[c0 + 1] + bet[c0 + 1]);
  o.z = f2b((v[2] - mean) * inv * gam[c0 + 2] + bet[c0 + 2]);
  o.w = f2b((v[3] - mean) * inv * gam[c0 + 3] + bet[c0 + 3]);
  *(ushort4*)&XBo[(size_t)row * 1024 + c0] = o;
}

extern "C" void kernel_launch(void* const* d_in, const int* in_sizes, int n_in,
                              void* d_out, int out_size, void* d_ws, size_t ws_size,
                              hipStream_t stream) {
  const float* q   = (const float*)d_in[0];
  const float* Wq  = (const float*)d_in[1];
  const float* bq  = (const float*)d_in[2];
  const float* Wk  = (const float*)d_in[3];
  const float* bk  = (const float*)d_in[4];
  const float* Wv  = (const float*)d_in[5];
  const float* bv  = (const float*)d_in[6];
  const float* Wm  = (const float*)d_in[7];
  const float* bm  = (const float*)d_in[8];
  const float* W1  = (const float*)d_in[9];
  const float* b1  = (const float*)d_in[10];
  const float* W2  = (const float*)d_in[11];
  const float* b2  = (const float*)d_in[12];
  const float* lng = (const float*)d_in[13];
  const float* lnb = (const float*)d_in[14];

  char* ws = (char*)d_ws;
  const size_t MB = 1u << 20;
  u16*  XB  = (u16*)(ws);             // 8 MB  bf16 x / xb
  u16*  WB  = (u16*)(ws + 8  * MB);   // 6 MB  packed Wq|Wk|Wv
  u16*  Qb  = (u16*)(ws + 14 * MB);   // 8 MB  fragment-linear Q (pre-scaled by 1/8)
  u16*  Kb  = (u16*)(ws + 22 * MB);   // 8 MB  fragment-linear K (reused as Hb for FFN)
  u16*  Vt  = (u16*)(ws + 30 * MB);   // 8 MB  fragment-linear V
  float* ml = (float*)(ws + 38 * MB); // 0.25 MB [b][h][q] denom l
  float* Vcs= (float*)(ws + 39 * MB); // 8 KB
  u16*  AOp = (u16*)(ws + 40 * MB);   // 32 MB bf16 attention partials [grp=ks*2+b][2048][1024]
  u16*  WB2 = (u16*)(ws + 72 * MB);   // 4 MB  packed W1|W2
  u16*  Hb  = Kb;

  pack_x  <<<4096, 256, 0, stream>>>(q, XB);
  pack_wT5<<<dim3(256, 5), 256, 0, stream>>>(Wq, Wk, Wv, W1, W2, WB, WB2);

  gemm_qkv<<<dim3(32, 24), 256, 0, stream>>>(XB, WB, bq, bk, bv, Qb, Kb, Vt);

  attn_ml <<<1024, 256, 0, stream>>>(Qb, Kb, ml);
  colsum_k<<<2048, 256, 0, stream>>>(Vt, Vcs);

  attn_fused<<<dim3(8, 64), 1024, 0, stream>>>(Qb, Kb, Vt, ml, Wm, AOp);

  ln_k<<<4096, 256, 0, stream>>>(AOp, q, bm, Vcs, lng, lnb, XB);

  gemm_bt64<1><<<dim3(64, 16), 256, 0, stream>>>(XB, WB2, b1, Hb, nullptr, nullptr);
  gemm_bt64<3><<<dim3(64, 16), 256, 0, stream>>>(Hb, WB2 + 1024 * 1024, b2, nullptr, XB, (float*)d_out);
}